// Round 1
// baseline (569.716 us; speedup 1.0000x reference)
//
#include <hip/hip_runtime.h>
#include <hip/hip_bf16.h>

#define N_NODES 100000
#define D_FEAT  256
#define N_ATT   256

// ---- types ----
typedef __bf16 bf16x8 __attribute__((ext_vector_type(8)));
typedef float  f32x16 __attribute__((ext_vector_type(16)));

// ---- helpers ----
__device__ __forceinline__ unsigned short bf16_rne(float f) {
    unsigned u = __float_as_uint(f);
    return (unsigned short)((u + 0x7fffu + ((u >> 16) & 1u)) >> 16);
}

// split f into hi (RNE bf16) + lo (truncated bf16 of remainder); f ~= hi + lo with ~2^-16 rel err
__device__ __forceinline__ void split1(float f, unsigned short& h, unsigned short& l) {
    h = bf16_rne(f);
    float fh = __uint_as_float((unsigned)h << 16);
    l = (unsigned short)(__float_as_uint(f - fh) >> 16);
}

// ============================================================================
// Kernel 1: split-K GEMM  C[v] += W @ x_v  (fp32 via bf16 hi/lo 3-product MFMA)
//   W: (256, 100000) row-major; x_v: (100000, 256) row-major; C: (3, 256, 256)
//   wg tile: 128(m) x 256(n) x chunk(K).  512 threads = 8 waves.
//   wave w: m-strip (w&3)*32, n-half (w>>2)*128 -> 4 frags of 32x32, acc 64 VGPR.
//   LDS: A_hi/A_lo 128x(32+8pad), B_hi/B_lo 256x(32+8pad) bf16 = 60 KB.
// ============================================================================
#define LDK 40   // padded LDS row stride in bf16 elems (stride 20 dwords -> conflict-free)

__global__ __launch_bounds__(512, 4) void gemm_split(
    const float* __restrict__ x1, const float* __restrict__ x2,
    const float* __restrict__ x3, const float* __restrict__ W,
    float* __restrict__ C, int chunk)
{
    extern __shared__ unsigned short lds[];
    unsigned short* Ah = lds;                 // 128*40
    unsigned short* Al = Ah + 128 * LDK;
    unsigned short* Bh = Al + 128 * LDK;      // 256*40
    unsigned short* Bl = Bh + 256 * LDK;

    const int bid = blockIdx.x;
    const int s   = bid / 6;        // split index
    const int pos = bid % 6;
    const int v   = pos >> 1;
    const int m0  = (pos & 1) * 128;
    const float* __restrict__ X = (v == 0) ? x1 : (v == 1) ? x2 : x3;

    const int ks = s * chunk;
    const int ke = min(ks + chunk, N_NODES);

    const int tid  = threadIdx.x;
    const int lane = tid & 63;
    const int wave = tid >> 6;
    const int mstrip = (wave & 3) * 32;    // wave m offset within 128
    const int nhalf  = (wave >> 2) * 128;  // wave n offset within 256

    // staging maps
    const int a_m  = tid >> 3;            // 0..63
    const int a_kk = (tid & 7) * 4;       // 0..28
    const int b_n64 = tid & 63;
    const int b_nb  = (tid >> 8) * 64;    // 0 or 64
    const int b_kq  = ((tid >> 6) & 3) ^ ((tid >> 3) & 3);  // XOR de-conflict

    f32x16 acc[4] = {};  // 4 n-blocks of 32x32

    const int l31 = lane & 31;
    const int khalf = (lane >> 5) * 8;

    for (int k0 = ks; k0 < ke; k0 += 32) {
        __syncthreads();  // protect LDS from previous iteration's readers

        // ---- stage A = W tile (128 m x 32 k), natural layout, split hi/lo ----
        #pragma unroll
        for (int p = 0; p < 2; ++p) {
            int m  = p * 64 + a_m;
            int kg = k0 + a_kk;
            float4 w4 = make_float4(0.f, 0.f, 0.f, 0.f);
            if (kg < ke)
                w4 = *(const float4*)(W + (size_t)(m0 + m) * N_NODES + kg);
            ushort4 h4, l4;
            split1(w4.x, h4.x, l4.x); split1(w4.y, h4.y, l4.y);
            split1(w4.z, h4.z, l4.z); split1(w4.w, h4.w, l4.w);
            *(ushort4*)(Ah + m * LDK + a_kk) = h4;
            *(ushort4*)(Al + m * LDK + a_kk) = l4;
        }
        // ---- stage B = x tile (32 k x 256 n) transposed into LDS [n][k] ----
        #pragma unroll
        for (int p = 0; p < 4; ++p) {
            int n  = (p >> 1) * 128 + b_nb + b_n64;
            int kb = (p & 1) * 16 + b_kq * 4;
            int kg = k0 + kb;
            float e0 = 0.f, e1 = 0.f, e2 = 0.f, e3 = 0.f;
            if (kg < ke) {
                const float* xp = X + (size_t)kg * D_FEAT + n;
                e0 = xp[0]; e1 = xp[D_FEAT]; e2 = xp[2 * D_FEAT]; e3 = xp[3 * D_FEAT];
            }
            ushort4 h4, l4;
            split1(e0, h4.x, l4.x); split1(e1, h4.y, l4.y);
            split1(e2, h4.z, l4.z); split1(e3, h4.w, l4.w);
            *(ushort4*)(Bh + n * LDK + kb) = h4;
            *(ushort4*)(Bl + n * LDK + kb) = l4;
        }
        __syncthreads();

        // ---- compute: 2 x K16 steps, 3-product hi/lo MFMA ----
        #pragma unroll
        for (int kk = 0; kk < 2; ++kk) {
            int kf = kk * 16 + khalf;
            int arow = mstrip + l31;
            bf16x8 ah = *(bf16x8*)(Ah + arow * LDK + kf);
            bf16x8 al = *(bf16x8*)(Al + arow * LDK + kf);
            #pragma unroll
            for (int nb = 0; nb < 4; ++nb) {
                int brow = nhalf + nb * 32 + l31;
                bf16x8 bh = *(bf16x8*)(Bh + brow * LDK + kf);
                bf16x8 bl = *(bf16x8*)(Bl + brow * LDK + kf);
                acc[nb] = __builtin_amdgcn_mfma_f32_32x32x16_bf16(ah, bh, acc[nb], 0, 0, 0);
                acc[nb] = __builtin_amdgcn_mfma_f32_32x32x16_bf16(ah, bl, acc[nb], 0, 0, 0);
                acc[nb] = __builtin_amdgcn_mfma_f32_32x32x16_bf16(al, bh, acc[nb], 0, 0, 0);
            }
        }
    }

    // ---- epilogue: atomic flush of split-K partials ----
    float* Cv = C + v * (N_ATT * D_FEAT);
    const int col = l31;
    const int rbase = 4 * (lane >> 5);
    #pragma unroll
    for (int nb = 0; nb < 4; ++nb) {
        int gj = nhalf + nb * 32 + col;
        #pragma unroll
        for (int r = 0; r < 16; ++r) {
            int row = (r & 3) + 8 * (r >> 2) + rbase;
            int gi = m0 + mstrip + row;
            unsafeAtomicAdd(Cv + gi * D_FEAT + gj, acc[nb][r]);
        }
    }
}

// ============================================================================
// Kernel 2: scores[v][j] = sum_i h[i] * tanh(C[v][i][j])   (atomic partial)
// ============================================================================
__global__ __launch_bounds__(256) void score_kernel(
    const float* __restrict__ C, const float* __restrict__ h,
    float* __restrict__ scores)
{
    const int v  = blockIdx.x >> 3;
    const int ig = blockIdx.x & 7;
    const int j  = threadIdx.x;
    const float* Cv = C + v * (N_ATT * D_FEAT);
    float s = 0.f;
    #pragma unroll 4
    for (int i = ig * 32; i < ig * 32 + 32; ++i)
        s += h[i] * tanhf(Cv[i * D_FEAT + j]);
    unsafeAtomicAdd(scores + v * D_FEAT + j, s);
}

// ============================================================================
// Kernel 3: out = softmax_v(scores)[v][j] * x_v  (streaming, inline softmax)
// ============================================================================
__device__ __forceinline__ float blend(float xa, float xb, float xc,
                                       float t0, float t1, float t2) {
    float m = fmaxf(t0, fmaxf(t1, t2));
    float e0 = __expf(t0 - m), e1 = __expf(t1 - m), e2 = __expf(t2 - m);
    float inv = 1.0f / (e0 + e1 + e2);
    return (e0 * xa + e1 * xb + e2 * xc) * inv;
}

__global__ __launch_bounds__(256) void out_kernel(
    const float* __restrict__ x1, const float* __restrict__ x2,
    const float* __restrict__ x3, const float* __restrict__ scores,
    float* __restrict__ out)
{
    size_t idx  = (size_t)blockIdx.x * 256 + threadIdx.x;  // float4 index
    size_t base = idx * 4;
    int j = (int)(base & (D_FEAT - 1));
    float4 a = *(const float4*)(x1 + base);
    float4 b = *(const float4*)(x2 + base);
    float4 c = *(const float4*)(x3 + base);
    float4 s0 = *(const float4*)(scores + j);
    float4 s1 = *(const float4*)(scores + D_FEAT + j);
    float4 s2 = *(const float4*)(scores + 2 * D_FEAT + j);
    float4 o;
    o.x = blend(a.x, b.x, c.x, s0.x, s1.x, s2.x);
    o.y = blend(a.y, b.y, c.y, s0.y, s1.y, s2.y);
    o.z = blend(a.z, b.z, c.z, s0.z, s1.z, s2.z);
    o.w = blend(a.w, b.w, c.w, s0.w, s1.w, s2.w);
    *(float4*)(out + base) = o;
}

// ============================================================================
extern "C" void kernel_launch(void* const* d_in, const int* in_sizes, int n_in,
                              void* d_out, int out_size, void* d_ws, size_t ws_size,
                              hipStream_t stream) {
    const float* x1 = (const float*)d_in[0];
    const float* x2 = (const float*)d_in[1];
    const float* x3 = (const float*)d_in[2];
    const float* W  = (const float*)d_in[3];
    const float* h  = (const float*)d_in[4];
    float* out = (float*)d_out;

    float* C      = (float*)d_ws;                 // 3*256*256 fp32 = 768 KB
    float* scores = C + 3 * N_ATT * D_FEAT;       // 3*256 fp32

    // zero the accumulators (ws is poisoned 0xAA before every timed launch)
    hipMemsetAsync(d_ws, 0, (3 * N_ATT * D_FEAT + 3 * D_FEAT) * sizeof(float), stream);

    // split-K GEMM: 85 splits x 6 (view, m-half) positions = 510 wgs (~2/CU)
    const int chunk = 1180;  // 85 * 1180 = 100300 >= 100000, multiple of 4
    gemm_split<<<dim3(510), dim3(512), 60 * 1024, stream>>>(x1, x2, x3, W, C, chunk);

    score_kernel<<<dim3(24), dim3(256), 0, stream>>>(C, h, scores);

    out_kernel<<<dim3((N_NODES * D_FEAT) / (4 * 256)), dim3(256), 0, stream>>>(
        x1, x2, x3, scores, out);
}

// Round 2
// 505.516 us; speedup vs baseline: 1.1270x; 1.1270x over previous
//
#include <hip/hip_runtime.h>
#include <hip/hip_bf16.h>

#define N_NODES 100000
#define D_FEAT  256
#define N_ATT   256

// ---- types ----
typedef __bf16 bf16x4 __attribute__((ext_vector_type(4)));
typedef __bf16 bf16x8 __attribute__((ext_vector_type(8)));
typedef float  f32x16 __attribute__((ext_vector_type(16)));

// ---- helpers ----
__device__ __forceinline__ unsigned short bf16_rne(float f) {
    unsigned u = __float_as_uint(f);
    return (unsigned short)((u + 0x7fffu + ((u >> 16) & 1u)) >> 16);
}

// split f into hi (RNE bf16) + lo (truncated bf16 of remainder)
__device__ __forceinline__ void split1(float f, unsigned short& h, unsigned short& l) {
    h = bf16_rne(f);
    float fh = __uint_as_float((unsigned)h << 16);
    l = (unsigned short)(__float_as_uint(f - fh) >> 16);
}

// load a bf16x8 fragment as two 8B reads (LDK=36 rows are 8B- but not 16B-aligned)
__device__ __forceinline__ bf16x8 ld8(const unsigned short* p) {
    bf16x4 lo = *(const bf16x4*)p;
    bf16x4 hi = *(const bf16x4*)(p + 4);
    return __builtin_shufflevector(lo, hi, 0, 1, 2, 3, 4, 5, 6, 7);
}

// ============================================================================
// Kernel 1: split-K GEMM  C[v] += W @ x_v
//   W kept as bf16 hi+lo (2 MFMA products); x rounded to bf16 RNE (1 operand).
//   wg tile: 128(m) x 256(n) x chunk(K). 512 thr = 8 waves; wave: 32m x 128n.
//   Register-prefetch double buffering: loads for iter k+1 issued before the
//   compute of iter k, so the vmcnt wait is covered by MFMA + barrier.
//   LDS: Ah/Al 128x36 + Bh 256x36 bf16 = 36 KB (18-dword stride, 2-way = free).
// ============================================================================
#define LDK 36

__global__ __launch_bounds__(512, 4) void gemm_split(
    const float* __restrict__ x1, const float* __restrict__ x2,
    const float* __restrict__ x3, const float* __restrict__ W,
    float* __restrict__ C, int chunk)
{
    extern __shared__ unsigned short lds[];
    unsigned short* Ah = lds;                 // 128*36
    unsigned short* Al = Ah + 128 * LDK;
    unsigned short* Bh = Al + 128 * LDK;      // 256*36   total 36864 B

    const int bid = blockIdx.x;
    const int s   = bid / 6;        // split index
    const int pos = bid % 6;
    const int v   = pos >> 1;
    const int m0  = (pos & 1) * 128;
    const float* __restrict__ X = (v == 0) ? x1 : (v == 1) ? x2 : x3;

    const int ks = s * chunk;
    const int ke = min(ks + chunk, N_NODES);

    const int tid  = threadIdx.x;
    const int lane = tid & 63;
    const int wave = tid >> 6;
    const int mstrip = (wave & 3) * 32;    // wave m offset within 128
    const int nhalf  = (wave >> 2) * 128;  // wave n offset within 256

    // staging maps
    const int a_m  = tid >> 3;             // 0..63
    const int a_kk = (tid & 7) * 4;        // 0..28
    const int b_n64 = tid & 63;
    const int b_nb  = (tid >> 8) * 64;     // 0 or 64
    const int b_kq  = ((tid >> 6) & 3) ^ ((tid >> 3) & 3);  // XOR de-conflict

    const int l31 = lane & 31;
    const int khalf = (lane >> 5) * 8;

    f32x16 acc[4] = {};  // 4 n-blocks of 32x32

    // ---- prefetch registers ----
    float4 pa[2];
    float  pb[4][4];

    auto issue = [&](int kg0) {
        #pragma unroll
        for (int p = 0; p < 2; ++p) {
            int kg = kg0 + a_kk;
            pa[p] = make_float4(0.f, 0.f, 0.f, 0.f);
            if (kg < ke)
                pa[p] = *(const float4*)(W + (size_t)(m0 + p * 64 + a_m) * N_NODES + kg);
        }
        #pragma unroll
        for (int p = 0; p < 4; ++p) {
            int n  = (p >> 1) * 128 + b_nb + b_n64;
            int kg = kg0 + (p & 1) * 16 + b_kq * 4;
            pb[p][0] = pb[p][1] = pb[p][2] = pb[p][3] = 0.f;
            if (kg < ke) {
                const float* xp = X + (size_t)kg * D_FEAT + n;
                pb[p][0] = xp[0];
                pb[p][1] = xp[D_FEAT];
                pb[p][2] = xp[2 * D_FEAT];
                pb[p][3] = xp[3 * D_FEAT];
            }
        }
    };

    issue(ks);  // prologue

    for (int k0 = ks; k0 < ke; k0 += 32) {
        __syncthreads();  // previous iteration's LDS readers are done

        // ---- stage A = W tile (hi/lo split) from prefetch regs ----
        #pragma unroll
        for (int p = 0; p < 2; ++p) {
            ushort4 h4, l4;
            split1(pa[p].x, h4.x, l4.x); split1(pa[p].y, h4.y, l4.y);
            split1(pa[p].z, h4.z, l4.z); split1(pa[p].w, h4.w, l4.w);
            int m = p * 64 + a_m;
            *(ushort4*)(Ah + m * LDK + a_kk) = h4;
            *(ushort4*)(Al + m * LDK + a_kk) = l4;
        }
        // ---- stage B = x tile (bf16 RNE), transposed [n][k] ----
        #pragma unroll
        for (int p = 0; p < 4; ++p) {
            int n  = (p >> 1) * 128 + b_nb + b_n64;
            int kb = (p & 1) * 16 + b_kq * 4;
            ushort4 h4;
            h4.x = bf16_rne(pb[p][0]); h4.y = bf16_rne(pb[p][1]);
            h4.z = bf16_rne(pb[p][2]); h4.w = bf16_rne(pb[p][3]);
            *(ushort4*)(Bh + n * LDK + kb) = h4;
        }

        // ---- issue loads for next iteration (in-flight across compute) ----
        if (k0 + 32 < ke) issue(k0 + 32);

        __syncthreads();

        // ---- compute: 2 x K16 steps, 2-product (Whi + Wlo) x bf16 ----
        #pragma unroll
        for (int kk = 0; kk < 2; ++kk) {
            int kf = kk * 16 + khalf;
            int arow = mstrip + l31;
            bf16x8 ah = ld8(Ah + arow * LDK + kf);
            bf16x8 al = ld8(Al + arow * LDK + kf);
            #pragma unroll
            for (int nb = 0; nb < 4; ++nb) {
                int brow = nhalf + nb * 32 + l31;
                bf16x8 bh = ld8(Bh + brow * LDK + kf);
                acc[nb] = __builtin_amdgcn_mfma_f32_32x32x16_bf16(ah, bh, acc[nb], 0, 0, 0);
                acc[nb] = __builtin_amdgcn_mfma_f32_32x32x16_bf16(al, bh, acc[nb], 0, 0, 0);
            }
        }
    }

    // ---- epilogue: atomic flush of split-K partials ----
    float* Cv = C + v * (N_ATT * D_FEAT);
    const int col = l31;
    const int rbase = 4 * (lane >> 5);
    #pragma unroll
    for (int nb = 0; nb < 4; ++nb) {
        int gj = nhalf + nb * 32 + col;
        #pragma unroll
        for (int r = 0; r < 16; ++r) {
            int row = (r & 3) + 8 * (r >> 2) + rbase;
            int gi = m0 + mstrip + row;
            unsafeAtomicAdd(Cv + gi * D_FEAT + gj, acc[nb][r]);
        }
    }
}

// ============================================================================
// Kernel 2: scores[v][j] = sum_i h[i] * tanh(C[v][i][j])   (atomic partial)
// ============================================================================
__global__ __launch_bounds__(256) void score_kernel(
    const float* __restrict__ C, const float* __restrict__ h,
    float* __restrict__ scores)
{
    const int v  = blockIdx.x >> 3;
    const int ig = blockIdx.x & 7;
    const int j  = threadIdx.x;
    const float* Cv = C + v * (N_ATT * D_FEAT);
    float s = 0.f;
    #pragma unroll 4
    for (int i = ig * 32; i < ig * 32 + 32; ++i)
        s += h[i] * tanhf(Cv[i * D_FEAT + j]);
    unsafeAtomicAdd(scores + v * D_FEAT + j, s);
}

// ============================================================================
// Kernel 3: out = softmax_v(scores)[v][j] * x_v  (streaming, inline softmax)
// ============================================================================
__device__ __forceinline__ float blend(float xa, float xb, float xc,
                                       float t0, float t1, float t2) {
    float m = fmaxf(t0, fmaxf(t1, t2));
    float e0 = __expf(t0 - m), e1 = __expf(t1 - m), e2 = __expf(t2 - m);
    float inv = 1.0f / (e0 + e1 + e2);
    return (e0 * xa + e1 * xb + e2 * xc) * inv;
}

__global__ __launch_bounds__(256) void out_kernel(
    const float* __restrict__ x1, const float* __restrict__ x2,
    const float* __restrict__ x3, const float* __restrict__ scores,
    float* __restrict__ out)
{
    size_t idx  = (size_t)blockIdx.x * 256 + threadIdx.x;  // float4 index
    size_t base = idx * 4;
    int j = (int)(base & (D_FEAT - 1));
    float4 a = *(const float4*)(x1 + base);
    float4 b = *(const float4*)(x2 + base);
    float4 c = *(const float4*)(x3 + base);
    float4 s0 = *(const float4*)(scores + j);
    float4 s1 = *(const float4*)(scores + D_FEAT + j);
    float4 s2 = *(const float4*)(scores + 2 * D_FEAT + j);
    float4 o;
    o.x = blend(a.x, b.x, c.x, s0.x, s1.x, s2.x);
    o.y = blend(a.y, b.y, c.y, s0.y, s1.y, s2.y);
    o.z = blend(a.z, b.z, c.z, s0.z, s1.z, s2.z);
    o.w = blend(a.w, b.w, c.w, s0.w, s1.w, s2.w);
    *(float4*)(out + base) = o;
}

// ============================================================================
extern "C" void kernel_launch(void* const* d_in, const int* in_sizes, int n_in,
                              void* d_out, int out_size, void* d_ws, size_t ws_size,
                              hipStream_t stream) {
    const float* x1 = (const float*)d_in[0];
    const float* x2 = (const float*)d_in[1];
    const float* x3 = (const float*)d_in[2];
    const float* W  = (const float*)d_in[3];
    const float* h  = (const float*)d_in[4];
    float* out = (float*)d_out;

    float* C      = (float*)d_ws;                 // 3*256*256 fp32 = 768 KB
    float* scores = C + 3 * N_ATT * D_FEAT;       // 3*256 fp32

    hipMemsetAsync(d_ws, 0, (3 * N_ATT * D_FEAT + 3 * D_FEAT) * sizeof(float), stream);

    // split-K GEMM: 85 splits x 6 (view, m-half) positions = 510 wgs (2/CU)
    const int chunk = 1180;  // 85 * 1180 = 100300 >= 100000, multiple of 4
    gemm_split<<<dim3(510), dim3(512), 512 * LDK * 2, stream>>>(x1, x2, x3, W, C, chunk);

    score_kernel<<<dim3(24), dim3(256), 0, stream>>>(C, h, scores);

    out_kernel<<<dim3((N_NODES * D_FEAT) / (4 * 256)), dim3(256), 0, stream>>>(
        x1, x2, x3, scores, out);
}

// Round 3
// 500.390 us; speedup vs baseline: 1.1385x; 1.0102x over previous
//
#include <hip/hip_runtime.h>
#include <hip/hip_bf16.h>

#define N_NODES 100000
#define D_FEAT  256
#define N_ATT   256

// ---- types ----
typedef __bf16 bf16x4 __attribute__((ext_vector_type(4)));
typedef __bf16 bf16x8 __attribute__((ext_vector_type(8)));
typedef float  f32x16 __attribute__((ext_vector_type(16)));

// ---- helpers ----
__device__ __forceinline__ unsigned short bf16_rne(float f) {
    unsigned u = __float_as_uint(f);
    return (unsigned short)((u + 0x7fffu + ((u >> 16) & 1u)) >> 16);
}

// split f into hi (RNE bf16) + lo (truncated bf16 of remainder)
__device__ __forceinline__ void split1(float f, unsigned short& h, unsigned short& l) {
    h = bf16_rne(f);
    float fh = __uint_as_float((unsigned)h << 16);
    l = (unsigned short)(__float_as_uint(f - fh) >> 16);
}

// load a bf16x8 fragment as two 8B reads (LDK=36 rows are 8B-aligned only)
__device__ __forceinline__ bf16x8 ld8(const unsigned short* p) {
    bf16x4 lo = *(const bf16x4*)p;
    bf16x4 hi = *(const bf16x4*)(p + 4);
    return __builtin_shufflevector(lo, hi, 0, 1, 2, 3, 4, 5, 6, 7);
}

// ============================================================================
// Kernel 1: split-K GEMM  C[v] += W @ x_v
//   W as bf16 hi+lo (2 MFMA products); x rounded to bf16 RNE.
//   wg tile: 128(m) x 256(n) x chunk(K). 512 thr = 8 waves; wave: 32m x 128n.
//   LDS DOUBLE-buffer, ONE barrier/iter:
//     issue loads(k+32) -> MFMA on buf[q] (covers HBM latency) ->
//     split+write buf[q^1] -> barrier.
//   chunk % 32 == 0 -> all k-tiles full -> no bounds guards in the hot loop.
//   LDS: (Ah/Al 128x36 + Bh 256x36) x 2 bufs = 73.7 KB -> 2 wg/CU.
// ============================================================================
#define LDK 36
#define BUF_SHORTS (512 * LDK)   // (128 + 128 + 256) * LDK per buffer

__global__ __launch_bounds__(512, 4) void gemm_split(
    const float* __restrict__ x1, const float* __restrict__ x2,
    const float* __restrict__ x3, const float* __restrict__ W,
    float* __restrict__ C, int chunk)
{
    extern __shared__ unsigned short lds[];

    const int bid = blockIdx.x;
    const int s   = bid / 6;        // split index
    const int pos = bid % 6;
    const int v   = pos >> 1;
    const int m0  = (pos & 1) * 128;
    const float* __restrict__ X = (v == 0) ? x1 : (v == 1) ? x2 : x3;

    const int ks = s * chunk;
    const int ke = min(ks + chunk, N_NODES);   // ke - ks is a multiple of 32

    const int tid  = threadIdx.x;
    const int lane = tid & 63;
    const int wave = tid >> 6;
    const int mstrip = (wave & 3) * 32;    // wave m offset within 128
    const int nhalf  = (wave >> 2) * 128;  // wave n offset within 256

    // staging maps
    const int a_m   = tid >> 3;            // 0..63
    const int a_kk  = (tid & 7) * 4;       // 0..28
    const int b_n64 = tid & 63;
    const int b_nb  = (tid >> 8) * 64;     // 0 or 64
    const int b_kq4 = (((tid >> 6) & 3) ^ ((tid >> 3) & 3)) * 4;  // XOR de-conflict

    const int l31 = lane & 31;
    const int khalf = (lane >> 5) * 8;

    f32x16 acc[4] = {};  // 4 n-blocks of 32x32
    float4 pa[2];
    float  pb[4][4];

    const float* Wb = W + (size_t)(m0 + a_m) * N_NODES + a_kk;

    auto issue = [&](int kg0) {
        #pragma unroll
        for (int p = 0; p < 2; ++p)
            pa[p] = *(const float4*)(Wb + (size_t)p * 64 * N_NODES + kg0);
        #pragma unroll
        for (int p = 0; p < 4; ++p) {
            int n  = (p >> 1) * 128 + b_nb + b_n64;
            int kg = kg0 + (p & 1) * 16 + b_kq4;
            const float* xp = X + (size_t)kg * D_FEAT + n;
            pb[p][0] = xp[0];
            pb[p][1] = xp[D_FEAT];
            pb[p][2] = xp[2 * D_FEAT];
            pb[p][3] = xp[3 * D_FEAT];
        }
    };

    auto stage = [&](unsigned short* buf) {
        unsigned short* Ah = buf;
        unsigned short* Al = buf + 128 * LDK;
        unsigned short* Bh = buf + 256 * LDK;
        #pragma unroll
        for (int p = 0; p < 2; ++p) {
            ushort4 h4, l4;
            split1(pa[p].x, h4.x, l4.x); split1(pa[p].y, h4.y, l4.y);
            split1(pa[p].z, h4.z, l4.z); split1(pa[p].w, h4.w, l4.w);
            int m = p * 64 + a_m;
            *(ushort4*)(Ah + m * LDK + a_kk) = h4;
            *(ushort4*)(Al + m * LDK + a_kk) = l4;
        }
        #pragma unroll
        for (int p = 0; p < 4; ++p) {
            int n  = (p >> 1) * 128 + b_nb + b_n64;
            int kb = (p & 1) * 16 + b_kq4;
            ushort4 h4;
            h4.x = bf16_rne(pb[p][0]); h4.y = bf16_rne(pb[p][1]);
            h4.z = bf16_rne(pb[p][2]); h4.w = bf16_rne(pb[p][3]);
            *(ushort4*)(Bh + n * LDK + kb) = h4;
        }
    };

    auto compute = [&](const unsigned short* buf) {
        const unsigned short* Ah = buf;
        const unsigned short* Al = buf + 128 * LDK;
        const unsigned short* Bh = buf + 256 * LDK;
        #pragma unroll
        for (int kk = 0; kk < 2; ++kk) {
            int kf = kk * 16 + khalf;
            int arow = mstrip + l31;
            bf16x8 ah = ld8(Ah + arow * LDK + kf);
            bf16x8 al = ld8(Al + arow * LDK + kf);
            #pragma unroll
            for (int nb = 0; nb < 4; ++nb) {
                int brow = nhalf + nb * 32 + l31;
                bf16x8 bh = ld8(Bh + brow * LDK + kf);
                acc[nb] = __builtin_amdgcn_mfma_f32_32x32x16_bf16(ah, bh, acc[nb], 0, 0, 0);
                acc[nb] = __builtin_amdgcn_mfma_f32_32x32x16_bf16(al, bh, acc[nb], 0, 0, 0);
            }
        }
    };

    // ---- prologue: stage tile ks into buf0 ----
    issue(ks);
    stage(lds);
    __syncthreads();

    // ---- main loop: one barrier per iteration ----
    int q = 0;
    for (int k0 = ks;;) {
        int k1 = k0 + 32;
        bool more = (k1 < ke);
        if (more) issue(k1);               // loads in flight across the MFMAs
        compute(lds + q * BUF_SHORTS);
        if (!more) break;
        stage(lds + (q ^ 1) * BUF_SHORTS); // vmcnt-wait lands here, after MFMA
        __syncthreads();
        q ^= 1;
        k0 = k1;
    }

    // ---- epilogue: atomic flush of split-K partials ----
    float* Cv = C + v * (N_ATT * D_FEAT);
    const int col = l31;
    const int rbase = 4 * (lane >> 5);
    #pragma unroll
    for (int nb = 0; nb < 4; ++nb) {
        int gj = nhalf + nb * 32 + col;
        #pragma unroll
        for (int r = 0; r < 16; ++r) {
            int row = (r & 3) + 8 * (r >> 2) + rbase;
            int gi = m0 + mstrip + row;
            unsafeAtomicAdd(Cv + gi * D_FEAT + gj, acc[nb][r]);
        }
    }
}

// ============================================================================
// Kernel 2: scores[v][j] = sum_i h[i] * tanh(C[v][i][j])   (atomic partial)
// ============================================================================
__global__ __launch_bounds__(256) void score_kernel(
    const float* __restrict__ C, const float* __restrict__ h,
    float* __restrict__ scores)
{
    const int v  = blockIdx.x >> 3;
    const int ig = blockIdx.x & 7;
    const int j  = threadIdx.x;
    const float* Cv = C + v * (N_ATT * D_FEAT);
    float s = 0.f;
    #pragma unroll 4
    for (int i = ig * 32; i < ig * 32 + 32; ++i)
        s += h[i] * tanhf(Cv[i * D_FEAT + j]);
    unsafeAtomicAdd(scores + v * D_FEAT + j, s);
}

// ============================================================================
// Kernel 3: out = softmax_v(scores)[v][j] * x_v  (streaming, inline softmax)
// ============================================================================
__device__ __forceinline__ float blend(float xa, float xb, float xc,
                                       float t0, float t1, float t2) {
    float m = fmaxf(t0, fmaxf(t1, t2));
    float e0 = __expf(t0 - m), e1 = __expf(t1 - m), e2 = __expf(t2 - m);
    float inv = 1.0f / (e0 + e1 + e2);
    return (e0 * xa + e1 * xb + e2 * xc) * inv;
}

__global__ __launch_bounds__(256) void out_kernel(
    const float* __restrict__ x1, const float* __restrict__ x2,
    const float* __restrict__ x3, const float* __restrict__ scores,
    float* __restrict__ out)
{
    size_t idx  = (size_t)blockIdx.x * 256 + threadIdx.x;  // float4 index
    size_t base = idx * 4;
    int j = (int)(base & (D_FEAT - 1));
    float4 a = *(const float4*)(x1 + base);
    float4 b = *(const float4*)(x2 + base);
    float4 c = *(const float4*)(x3 + base);
    float4 s0 = *(const float4*)(scores + j);
    float4 s1 = *(const float4*)(scores + D_FEAT + j);
    float4 s2 = *(const float4*)(scores + 2 * D_FEAT + j);
    float4 o;
    o.x = blend(a.x, b.x, c.x, s0.x, s1.x, s2.x);
    o.y = blend(a.y, b.y, c.y, s0.y, s1.y, s2.y);
    o.z = blend(a.z, b.z, c.z, s0.z, s1.z, s2.z);
    o.w = blend(a.w, b.w, c.w, s0.w, s1.w, s2.w);
    *(float4*)(out + base) = o;
}

// ============================================================================
extern "C" void kernel_launch(void* const* d_in, const int* in_sizes, int n_in,
                              void* d_out, int out_size, void* d_ws, size_t ws_size,
                              hipStream_t stream) {
    const float* x1 = (const float*)d_in[0];
    const float* x2 = (const float*)d_in[1];
    const float* x3 = (const float*)d_in[2];
    const float* W  = (const float*)d_in[3];
    const float* h  = (const float*)d_in[4];
    float* out = (float*)d_out;

    float* C      = (float*)d_ws;                 // 3*256*256 fp32 = 768 KB
    float* scores = C + 3 * N_ATT * D_FEAT;       // 3*256 fp32

    hipMemsetAsync(d_ws, 0, (3 * N_ATT * D_FEAT + 3 * D_FEAT) * sizeof(float), stream);

    // split-K GEMM: 85 splits x 6 (view, m-half) positions = 510 wgs (2/CU)
    // chunk % 32 == 0 and 85*1184 >= 100000; last split gets 544 = 17 full tiles
    const int chunk = 1184;
    gemm_split<<<dim3(510), dim3(512), 2 * BUF_SHORTS * 2, stream>>>(x1, x2, x3, W, C, chunk);

    score_kernel<<<dim3(24), dim3(256), 0, stream>>>(C, h, scores);

    out_kernel<<<dim3((N_NODES * D_FEAT) / (4 * 256)), dim3(256), 0, stream>>>(
        x1, x2, x3, scores, out);
}

// Round 4
// 496.808 us; speedup vs baseline: 1.1468x; 1.0072x over previous
//
#include <hip/hip_runtime.h>
#include <hip/hip_bf16.h>

#define N_NODES 100000
#define D_FEAT  256
#define N_ATT   256

// ---- types ----
typedef __bf16 bf16x4 __attribute__((ext_vector_type(4)));
typedef __bf16 bf16x8 __attribute__((ext_vector_type(8)));
typedef float  f32x16 __attribute__((ext_vector_type(16)));

// ---- helpers ----
__device__ __forceinline__ unsigned short bf16_rne(float f) {
    unsigned u = __float_as_uint(f);
    return (unsigned short)((u + 0x7fffu + ((u >> 16) & 1u)) >> 16);
}

// split f into hi (RNE bf16) + lo (truncated bf16 of remainder)
__device__ __forceinline__ void split1(float f, unsigned short& h, unsigned short& l) {
    h = bf16_rne(f);
    float fh = __uint_as_float((unsigned)h << 16);
    l = (unsigned short)(__float_as_uint(f - fh) >> 16);
}

// load a bf16x8 fragment as two 8B reads (LDK=36 rows are 8B-aligned only)
__device__ __forceinline__ bf16x8 ld8(const unsigned short* p) {
    bf16x4 lo = *(const bf16x4*)p;
    bf16x4 hi = *(const bf16x4*)(p + 4);
    return __builtin_shufflevector(lo, hi, 0, 1, 2, 3, 4, 5, 6, 7);
}

// ============================================================================
// Kernel 1: split-K GEMM  C[v] += W @ x_v
//   W as bf16 hi+lo (2 MFMA products); x rounded to bf16 RNE.
//   wg tile: 128(m) x 256(n) x chunk(K). 512 thr = 8 waves; wave: 32m x 128n.
//   LDS double-buffer, one barrier/iter:
//     issue loads(k+32) -> MFMA on buf[q] -> split+write buf[q^1] -> barrier.
//   R4 change: x-staging k-quad is WAVE-UNIFORM (no per-8-lane XOR), so every
//   x global load is one contiguous 256 B wave transaction (was 8 x 32 B
//   scatter -> ~128 transactions/wave-iter; the latency wall of R2/R3).
//   Register budget held at R3 level (VGPR64 + acc64 = 128 = 4 waves/SIMD).
// ============================================================================
#define LDK 36
#define BUF_SHORTS (512 * LDK)   // (128 + 128 + 256) * LDK per buffer

__global__ __launch_bounds__(512, 4) void gemm_split(
    const float* __restrict__ x1, const float* __restrict__ x2,
    const float* __restrict__ x3, const float* __restrict__ W,
    float* __restrict__ C, int chunk)
{
    extern __shared__ unsigned short lds[];

    const int bid = blockIdx.x;
    const int s   = bid / 6;        // split index
    const int pos = bid % 6;
    const int v   = pos >> 1;
    const int m0  = (pos & 1) * 128;
    const float* __restrict__ X = (v == 0) ? x1 : (v == 1) ? x2 : x3;

    const int ks = s * chunk;
    const int ke = min(ks + chunk, N_NODES);   // ke - ks is a multiple of 32

    const int tid  = threadIdx.x;
    const int lane = tid & 63;
    const int wave = tid >> 6;
    const int mstrip = (wave & 3) * 32;    // wave m offset within 128
    const int nhalf  = (wave >> 2) * 128;  // wave n offset within 256

    // staging maps
    const int a_m   = tid >> 3;            // 0..63
    const int a_kk  = (tid & 7) * 4;       // 0..28
    const int b_n64 = tid & 63;
    const int b_nb  = (tid >> 8) * 64;     // 0 or 64
    const int b_kq4 = ((tid >> 6) & 3) * 4;  // WAVE-UNIFORM k-quad (no XOR)

    const int l31 = lane & 31;
    const int khalf = (lane >> 5) * 8;

    f32x16 acc[4] = {};  // 4 n-blocks of 32x32
    float4 pa[2];
    float  pb[4][4];

    const float* Wb = W + (size_t)(m0 + a_m) * N_NODES + a_kk;

    auto issue = [&](int kg0) {
        #pragma unroll
        for (int p = 0; p < 2; ++p)
            pa[p] = *(const float4*)(Wb + (size_t)p * 64 * N_NODES + kg0);
        #pragma unroll
        for (int p = 0; p < 4; ++p) {
            int n  = (p >> 1) * 128 + b_nb + b_n64;
            int kg = kg0 + (p & 1) * 16 + b_kq4;
            const float* xp = X + (size_t)kg * D_FEAT + n;
            pb[p][0] = xp[0];             // each: 64 consecutive floats across
            pb[p][1] = xp[D_FEAT];        // the wave = one 256 B transaction
            pb[p][2] = xp[2 * D_FEAT];
            pb[p][3] = xp[3 * D_FEAT];
        }
    };

    auto stage = [&](unsigned short* buf) {
        unsigned short* Ah = buf;
        unsigned short* Al = buf + 128 * LDK;
        unsigned short* Bh = buf + 256 * LDK;
        #pragma unroll
        for (int p = 0; p < 2; ++p) {
            ushort4 h4, l4;
            split1(pa[p].x, h4.x, l4.x); split1(pa[p].y, h4.y, l4.y);
            split1(pa[p].z, h4.z, l4.z); split1(pa[p].w, h4.w, l4.w);
            int m = p * 64 + a_m;
            *(ushort4*)(Ah + m * LDK + a_kk) = h4;
            *(ushort4*)(Al + m * LDK + a_kk) = l4;
        }
        #pragma unroll
        for (int p = 0; p < 4; ++p) {
            int n  = (p >> 1) * 128 + b_nb + b_n64;
            int kb = (p & 1) * 16 + b_kq4;
            ushort4 h4;
            h4.x = bf16_rne(pb[p][0]); h4.y = bf16_rne(pb[p][1]);
            h4.z = bf16_rne(pb[p][2]); h4.w = bf16_rne(pb[p][3]);
            *(ushort4*)(Bh + n * LDK + kb) = h4;
        }
    };

    auto compute = [&](const unsigned short* buf) {
        const unsigned short* Ah = buf;
        const unsigned short* Al = buf + 128 * LDK;
        const unsigned short* Bh = buf + 256 * LDK;
        #pragma unroll
        for (int kk = 0; kk < 2; ++kk) {
            int kf = kk * 16 + khalf;
            int arow = mstrip + l31;
            bf16x8 ah = ld8(Ah + arow * LDK + kf);
            bf16x8 al = ld8(Al + arow * LDK + kf);
            #pragma unroll
            for (int nb = 0; nb < 4; ++nb) {
                int brow = nhalf + nb * 32 + l31;
                bf16x8 bh = ld8(Bh + brow * LDK + kf);
                acc[nb] = __builtin_amdgcn_mfma_f32_32x32x16_bf16(ah, bh, acc[nb], 0, 0, 0);
                acc[nb] = __builtin_amdgcn_mfma_f32_32x32x16_bf16(al, bh, acc[nb], 0, 0, 0);
            }
        }
    };

    // ---- prologue: stage tile ks into buf0 ----
    issue(ks);
    stage(lds);
    __syncthreads();

    // ---- main loop: one barrier per iteration ----
    int q = 0;
    for (int k0 = ks;;) {
        int k1 = k0 + 32;
        bool more = (k1 < ke);
        if (more) issue(k1);               // loads in flight across the MFMAs
        compute(lds + q * BUF_SHORTS);
        if (!more) break;
        stage(lds + (q ^ 1) * BUF_SHORTS); // vmcnt-wait lands here, after MFMA
        __syncthreads();
        q ^= 1;
        k0 = k1;
    }

    // ---- epilogue: atomic flush of split-K partials ----
    float* Cv = C + v * (N_ATT * D_FEAT);
    const int col = l31;
    const int rbase = 4 * (lane >> 5);
    #pragma unroll
    for (int nb = 0; nb < 4; ++nb) {
        int gj = nhalf + nb * 32 + col;
        #pragma unroll
        for (int r = 0; r < 16; ++r) {
            int row = (r & 3) + 8 * (r >> 2) + rbase;
            int gi = m0 + mstrip + row;
            unsafeAtomicAdd(Cv + gi * D_FEAT + gj, acc[nb][r]);
        }
    }
}

// ============================================================================
// Kernel 2: scores[v][j] = sum_i h[i] * tanh(C[v][i][j])   (atomic partial)
// ============================================================================
__global__ __launch_bounds__(256) void score_kernel(
    const float* __restrict__ C, const float* __restrict__ h,
    float* __restrict__ scores)
{
    const int v  = blockIdx.x >> 3;
    const int ig = blockIdx.x & 7;
    const int j  = threadIdx.x;
    const float* Cv = C + v * (N_ATT * D_FEAT);
    float s = 0.f;
    #pragma unroll 4
    for (int i = ig * 32; i < ig * 32 + 32; ++i)
        s += h[i] * tanhf(Cv[i * D_FEAT + j]);
    unsafeAtomicAdd(scores + v * D_FEAT + j, s);
}

// ============================================================================
// Kernel 3: out = softmax_v(scores)[v][j] * x_v  (streaming, inline softmax)
// ============================================================================
__device__ __forceinline__ float blend(float xa, float xb, float xc,
                                       float t0, float t1, float t2) {
    float m = fmaxf(t0, fmaxf(t1, t2));
    float e0 = __expf(t0 - m), e1 = __expf(t1 - m), e2 = __expf(t2 - m);
    float inv = 1.0f / (e0 + e1 + e2);
    return (e0 * xa + e1 * xb + e2 * xc) * inv;
}

__global__ __launch_bounds__(256) void out_kernel(
    const float* __restrict__ x1, const float* __restrict__ x2,
    const float* __restrict__ x3, const float* __restrict__ scores,
    float* __restrict__ out)
{
    size_t idx  = (size_t)blockIdx.x * 256 + threadIdx.x;  // float4 index
    size_t base = idx * 4;
    int j = (int)(base & (D_FEAT - 1));
    float4 a = *(const float4*)(x1 + base);
    float4 b = *(const float4*)(x2 + base);
    float4 c = *(const float4*)(x3 + base);
    float4 s0 = *(const float4*)(scores + j);
    float4 s1 = *(const float4*)(scores + D_FEAT + j);
    float4 s2 = *(const float4*)(scores + 2 * D_FEAT + j);
    float4 o;
    o.x = blend(a.x, b.x, c.x, s0.x, s1.x, s2.x);
    o.y = blend(a.y, b.y, c.y, s0.y, s1.y, s2.y);
    o.z = blend(a.z, b.z, c.z, s0.z, s1.z, s2.z);
    o.w = blend(a.w, b.w, c.w, s0.w, s1.w, s2.w);
    *(float4*)(out + base) = o;
}

// ============================================================================
extern "C" void kernel_launch(void* const* d_in, const int* in_sizes, int n_in,
                              void* d_out, int out_size, void* d_ws, size_t ws_size,
                              hipStream_t stream) {
    const float* x1 = (const float*)d_in[0];
    const float* x2 = (const float*)d_in[1];
    const float* x3 = (const float*)d_in[2];
    const float* W  = (const float*)d_in[3];
    const float* h  = (const float*)d_in[4];
    float* out = (float*)d_out;

    float* C      = (float*)d_ws;                 // 3*256*256 fp32 = 768 KB
    float* scores = C + 3 * N_ATT * D_FEAT;       // 3*256 fp32

    hipMemsetAsync(d_ws, 0, (3 * N_ATT * D_FEAT + 3 * D_FEAT) * sizeof(float), stream);

    // split-K GEMM: 85 splits x 6 (view, m-half) positions = 510 wgs (2/CU)
    const int chunk = 1184;  // 37 full 32-k tiles; last split 544 = 17 tiles
    gemm_split<<<dim3(510), dim3(512), 2 * BUF_SHORTS * 2, stream>>>(x1, x2, x3, W, C, chunk);

    score_kernel<<<dim3(24), dim3(256), 0, stream>>>(C, h, scores);

    out_kernel<<<dim3((N_NODES * D_FEAT) / (4 * 256)), dim3(256), 0, stream>>>(
        x1, x2, x3, scores, out);
}